// Round 17
// baseline (41.248 us; speedup 1.0000x reference)
//
#include <hip/hip_runtime.h>

#define NBINS  128               // uniform bins in x-space over [-6, 6]
#define NCLS   20
#define CDIM   21
#define HW     (512 * 512)
#define NPIX   (8 * HW)
#define NCHUNK 1024
#define CHUNK  (NPIX / NCHUNK)   // 2048 pixels/block; divides HW
#define HSZ    (NCLS * NBINS)    // 2560 packed u32 per block
#define XSCALE 10.6666667f       // 128/12
#define XBIAS  64.0f             // 6 * XSCALE

__device__ __forceinline__ float4 gld_f4(const float* p) {
    float4 r;
    asm volatile("global_load_dwordx4 %0, %1, off" : "=v"(r) : "v"(p));
    return r;
}
__device__ __forceinline__ int4 gld_i4(const int* p) {
    int4 r;
    asm volatile("global_load_dwordx4 %0, %1, off" : "=v"(r) : "v"(p));
    return r;
}

// One block = 2048 pixels via 512 threads (4 px/thread, single tile), all 20
// classes, binned in x-space (monotone in sigmoid; positives bin at -x on the
// symmetric grid). 5 phases of 4 channels, 1-ahead counted-vmcnt pipeline:
// wait vmcnt(4) -> compute G_g -> issue G_{g+2} into the buffer just consumed.
// Lean register state (buf[2][4]=32 + label=4 VGPR pinned) to fit the 84-VGPR
// budget of launch_bounds(512,6): 6 waves/SIMD = 24 waves/CU (vs 16 at R13's
// 128-VGPR config). Grid 1024 blocks so 3 blocks/CU can actually co-reside.
// Output: packed per-block u32 histogram (cnt lo16 | pos hi16), plain stores,
// no atomics, no pre-zeroing, no device fences.
__global__ __launch_bounds__(512, 6) void lovasz_hist(const float* __restrict__ pred,
                                                      const int* __restrict__ label,
                                                      unsigned* __restrict__ g_part) {
    __shared__ unsigned s_hist[HSZ];   // 10 KB
    const int tid = threadIdx.x;

    const long base = (long)blockIdx.x * CHUNK;
    const int  b    = (int)(base / HW);
    const long hw0  = base - (long)b * HW;
    const float* pbase = pred + ((long)b * CDIM + 1) * HW + hw0 + tid * 4;

    // Prologue: label + G0 + G1 issued (9 outstanding).
    const int4 l = gld_i4(label + base + tid * 4);
    float4 buf[2][4];
#pragma unroll
    for (int gg = 0; gg < 2; ++gg)
#pragma unroll
        for (int k = 0; k < 4; ++k)
            buf[gg][k] = gld_f4(pbase + (long)(gg * 4 + k) * HW);

    // zero LDS + barrier under the load latency
    for (int i = tid; i < HSZ; i += 512) s_hist[i] = 0u;
    __syncthreads();

    auto compute4 = [&](const float4* x, int cbase) {
#pragma unroll
        for (int j = 0; j < 4; ++j) {
            const int lv = (j == 0) ? l.x : (j == 1) ? l.y : (j == 2) ? l.z : l.w;
#pragma unroll
            for (int k = 0; k < 4; ++k) {
                const float xv = (j == 0) ? x[k].x : (j == 1) ? x[k].y
                               : (j == 2) ? x[k].z : x[k].w;
                const bool  pos = (lv == cbase + k + 1);
                const float t   = pos ? -xv : xv;     // error = sigmoid(t)
                const float bf  = fminf(fmaxf(__builtin_fmaf(t, XSCALE, XBIAS), 0.0f), 127.0f);
                const int   bin = (int)bf;
                atomicAdd(&s_hist[(cbase + k) * NBINS + bin], pos ? 0x10001u : 1u);
            }
        }
    };

    // vmcnt ledger: g=0 wait(4) retires l+G0 (G1 in flight); steady state
    // keeps exactly one group (4 loads) outstanding; drain only at g=4.
#pragma unroll
    for (int g = 0; g < 5; ++g) {
        if (g < 4) asm volatile("s_waitcnt vmcnt(4)" ::: "memory");
        else       asm volatile("s_waitcnt vmcnt(0)" ::: "memory");
        __builtin_amdgcn_sched_barrier(0);
        compute4(buf[g & 1], g * 4);
        if (g + 2 < 5) {       // refill the just-consumed buffer with G_{g+2}
#pragma unroll
            for (int k = 0; k < 4; ++k)
                buf[g & 1][k] = gld_f4(pbase + (long)((g + 2) * 4 + k) * HW);
        }
    }

    __syncthreads();

    // Plain coalesced stores of the packed per-block histogram.
    unsigned* gp = g_part + (size_t)blockIdx.x * HSZ;
    for (int i = tid; i < HSZ; i += 512) gp[i] = s_hist[i];
}

// Parallel reduce: P[1024][2560] packed -> H[2560] u64 (cnt lo32 | pos hi32).
// 160 blocks x 256 thr; block bb owns 16 bins; thread t: bin bb*16+(t&15),
// replica chunk t>>4 (64 replicas, unpacked every 8: 8*2048 < 2^16).
__global__ __launch_bounds__(256) void lovasz_reduce(const unsigned* __restrict__ g_part,
                                                     unsigned long long* __restrict__ H) {
    const int t  = threadIdx.x;
    const int i  = blockIdx.x * 16 + (t & 15);
    const int rc = t >> 4;            // 0..15, 64 replicas each
    const unsigned* gp = g_part + i;

    unsigned vc = 0, vp = 0;
#pragma unroll
    for (int bt = 0; bt < 8; ++bt) {
        unsigned pk = 0;
#pragma unroll
        for (int k = 0; k < 8; ++k)
            pk += gp[(size_t)(rc * 64 + bt * 8 + k) * HSZ];
        vc += pk & 0xFFFFu;
        vp += pk >> 16;
    }
    __shared__ unsigned s_c[16][16], s_p[16][16];
    s_c[rc][t & 15] = vc;
    s_p[rc][t & 15] = vp;
    __syncthreads();
    if (t < 16) {
        unsigned c = 0, p = 0;
#pragma unroll
        for (int r = 0; r < 16; ++r) { c += s_c[r][t]; p += s_p[r][t]; }
        H[blockIdx.x * 16 + t] = (unsigned long long)c | ((unsigned long long)p << 32);
    }
}

// Fused scan+final: one wave per class (2 bins/lane), shfl butterfly prefix
// scan in descending-error order, Lovasz-grad weighted sum, block reduce.
__global__ __launch_bounds__(1024) void lovasz_scan(const unsigned long long* __restrict__ H,
                                                    float* __restrict__ out) {
    __shared__ float cls_sum[NCLS];
    __shared__ float cls_cnt[NCLS];
    const int wid  = threadIdx.x >> 6;
    const int lane = threadIdx.x & 63;

#pragma unroll
    for (int it = 0; it < 2; ++it) {
        const int cls = it * 16 + wid;
        if (cls < NCLS) {
            // lane covers descending positions d0=2*lane (bin 127-2l), d1 (bin 126-2l)
            const int bin_lo = 126 - 2 * lane;
            const ulonglong2 v = *reinterpret_cast<const ulonglong2*>(H + cls * NBINS + bin_lo);
            const int vc1 = (int)(v.x & 0xFFFFFFFFull), vp1 = (int)(v.x >> 32);  // d1
            const int vc0 = (int)(v.y & 0xFFFFFFFFull), vp0 = (int)(v.y >> 32);  // d0
            const int sc = vc0 + vc1, sp = vp0 + vp1;
            int ic = sc, ip = sp;                 // inclusive wave scan over lanes
#pragma unroll
            for (int d = 1; d < 64; d <<= 1) {
                const int tc = __shfl_up(ic, d, 64);
                const int tp = __shfl_up(ip, d, 64);
                if (lane >= d) { ic += tc; ip += tp; }
            }
            const int G   = __shfl(ip, 63, 64);         // total positives
            const int ec0 = ic - sc, ep0 = ip - sp;     // exclusive prefix at d0
            float contrib = 0.0f;
            if (G > 0) {
                const float fG = (float)G;
                auto J = [&](int i, int m) {
                    return 1.0f - (fG - (float)m) / (fG + (float)(i - m));
                };
                auto EMID = [&](int bn) {
                    const float xm = ((float)bn + 0.5f) * (12.0f / (float)NBINS) - 6.0f;
                    return 1.0f / (1.0f + __expf(-xm));
                };
                if (vc0) {
                    contrib += EMID(127 - 2 * lane) *
                               (J(ec0 + vc0, ep0 + vp0) - J(ec0, ep0));
                }
                if (vc1) {
                    const int ec = ec0 + vc0, ep = ep0 + vp0;
                    contrib += EMID(126 - 2 * lane) *
                               (J(ec + vc1, ep + vp1) - J(ec, ep));
                }
            }
#pragma unroll
            for (int d = 32; d > 0; d >>= 1) contrib += __shfl_down(contrib, d, 64);
            if (lane == 0) {
                cls_sum[cls] = contrib;
                cls_cnt[cls] = (G > 0) ? 1.0f : 0.0f;
            }
        }
    }
    __syncthreads();
    if (threadIdx.x == 0) {
        float s = 0.0f, n = 0.0f;
        for (int c = 0; c < NCLS; ++c) { s += cls_sum[c]; n += cls_cnt[c]; }
        out[0] = s / n;
    }
}

extern "C" void kernel_launch(void* const* d_in, const int* in_sizes, int n_in,
                              void* d_out, int out_size, void* d_ws, size_t ws_size,
                              hipStream_t stream) {
    const float* pred  = (const float*)d_in[0];
    const int*   label = (const int*)d_in[1];

    unsigned* g_part = (unsigned*)d_ws;                       // 1024*2560*4B = 10.5 MB
    unsigned long long* H = (unsigned long long*)(g_part + (size_t)NCHUNK * HSZ);
    float* out = (float*)d_out;

    lovasz_hist<<<NCHUNK, 512, 0, stream>>>(pred, label, g_part);
    lovasz_reduce<<<HSZ / 16, 256, 0, stream>>>(g_part, H);
    lovasz_scan<<<1, 1024, 0, stream>>>(H, out);
}